// Round 9
// baseline (119.144 us; speedup 1.0000x reference)
//
#include <hip/hip_runtime.h>

typedef __attribute__((ext_vector_type(4))) float f32x4;
typedef __attribute__((ext_vector_type(8))) short s16x8;
typedef __attribute__((ext_vector_type(4))) short s16x4;
typedef __attribute__((ext_vector_type(8))) __bf16 bf16x8;

#define B_ 64
#define LQ_ 32
#define LP_ 256
#define H_ 768
#define D_ 128

__device__ __forceinline__ short cvt_bf16(float f) {
  unsigned u = __builtin_bit_cast(unsigned, f);
  unsigned r = (u + 0x7fffu + ((u >> 16) & 1u)) >> 16;
  return (short)r;
}
__device__ __forceinline__ float frombf(short h) {
  unsigned v = ((unsigned)(unsigned short)h) << 16;
  return __builtin_bit_cast(float, v);
}
__device__ __forceinline__ f32x4 mfma16(s16x8 a, s16x8 b, f32x4 c) {
  return __builtin_amdgcn_mfma_f32_16x16x32_bf16(
      __builtin_bit_cast(bf16x8, a), __builtin_bit_cast(bf16x8, b), c, 0, 0, 0);
}
__device__ __forceinline__ s16x8 cvt8(f32x4 a, f32x4 b) {
  s16x8 r;
  r[0] = __builtin_bit_cast(short, (__bf16)a[0]);
  r[1] = __builtin_bit_cast(short, (__bf16)a[1]);
  r[2] = __builtin_bit_cast(short, (__bf16)a[2]);
  r[3] = __builtin_bit_cast(short, (__bf16)a[3]);
  r[4] = __builtin_bit_cast(short, (__bf16)b[0]);
  r[5] = __builtin_bit_cast(short, (__bf16)b[1]);
  r[6] = __builtin_bit_cast(short, (__bf16)b[2]);
  r[7] = __builtin_bit_cast(short, (__bf16)b[3]);
  return r;
}

// ---------------- K1: fused pre-work ----------------
__global__ __launch_bounds__(256) void k_pre(const float* __restrict__ W,
                                             const int* __restrict__ pm,
                                             const int* __restrict__ nm,
                                             short* __restrict__ Wt,
                                             float* __restrict__ mf) {
  __shared__ float tile[32][33];
  int bid = blockIdx.x;
  int t = threadIdx.x;
  if (bid < 96) {
    int k0 = (bid % 24) * 32, n0 = (bid / 24) * 32;
    int r = t >> 3, c4 = (t & 7) << 2;
    f32x4 v = *(const f32x4*)(W + (size_t)(k0 + r) * D_ + n0 + c4);
    tile[r][c4 + 0] = v[0]; tile[r][c4 + 1] = v[1];
    tile[r][c4 + 2] = v[2]; tile[r][c4 + 3] = v[3];
    __syncthreads();
    s16x4 o;
    o[0] = cvt_bf16(tile[c4 + 0][r]);
    o[1] = cvt_bf16(tile[c4 + 1][r]);
    o[2] = cvt_bf16(tile[c4 + 2][r]);
    o[3] = cvt_bf16(tile[c4 + 3][r]);
    *(s16x4*)(Wt + (size_t)(n0 + r) * H_ + k0 + c4) = o;
  } else {
    int i = (bid - 96) * 256 + t;
    float ninf = -__builtin_inff();
    mf[i]         = pm[i] ? 0.f : ninf;
    mf[16384 + i] = nm[i] ? 0.f : ninf;
  }
}

// ---------------- K2: projection GEMM — inline-asm loads, counted vmcnt ----------------
// 1088 blocks x 256 thr (4 waves). Block = 32 rows x 128 cols. Wave (wm,wc) =
// 16 rows x 64 cols, no LDS, no barriers. 24 BK=32 chunks; 6 asm loads/chunk
// (immediate offsets), 4 named slots, steady vmcnt(18). acc via constant idx.
__global__ __launch_bounds__(256, 3) void k_proj(
    const float* __restrict__ Hq, const float* __restrict__ Hp, const float* __restrict__ Hn,
    const short* __restrict__ Wt, const float* __restrict__ bias,
    short* __restrict__ Xq, short* __restrict__ Xp, short* __restrict__ Xn,
    float* __restrict__ ps) {
  int bid = blockIdx.x;
  const float* Hs; short* X; int brow0, ub;
  if (bid < 64)       { Hs = Hq; X = Xq; brow0 = bid * 32;         ub = bid * 2; }
  else if (bid < 576) { Hs = Hp; X = Xp; brow0 = (bid - 64) * 32;  ub = 128 + (bid - 64) * 2; }
  else                { Hs = Hn; X = Xn; brow0 = (bid - 576) * 32; ub = 1152 + (bid - 576) * 2; }
  int t = threadIdx.x, lane = t & 63, w = t >> 6;
  int wm = w & 1, wc = w >> 1;
  int lhi = lane >> 4, llo = lane & 15;
  int row0 = brow0 + wm * 16;
  int unit = ub + wm;

  const float* ap  = Hs + (size_t)(row0 + llo) * H_ + lhi * 8;
  const short* bp0 = Wt + (size_t)(wc * 64 + llo) * H_ + lhi * 8;
  const short* bp1 = bp0 + (size_t)16 * H_;
  const short* bp2 = bp0 + (size_t)32 * H_;
  const short* bp3 = bp0 + (size_t)48 * H_;

  // 4 slots, all named (asm outputs -> cannot be coalesced/sunk)
  f32x4 a0_0, a1_0, a0_1, a1_1, a0_2, a1_2, a0_3, a1_3;
  s16x8 b0_0, b1_0, b2_0, b3_0, b0_1, b1_1, b2_1, b3_1;
  s16x8 b0_2, b1_2, b2_2, b3_2, b0_3, b1_3, b2_3, b3_3;

#define GL(dst, base, OFF)                                               \
  asm volatile("global_load_dwordx4 %0, %1, off offset:%2"               \
               : "=v"(dst) : "v"(base), "n"(OFF));

#define ISSUE(C, S)                                                      \
  GL(a0_##S, ap,  (C) * 128)                                             \
  GL(a1_##S, ap,  (C) * 128 + 16)                                        \
  GL(b0_##S, bp0, (C) * 64)                                              \
  GL(b1_##S, bp1, (C) * 64)                                              \
  GL(b2_##S, bp2, (C) * 64)                                              \
  GL(b3_##S, bp3, (C) * 64)

  f32x4 acc[4] = {};

#define STEPC(C, S, N)                                                   \
  {                                                                      \
    asm volatile("s_waitcnt vmcnt(%0)" :: "n"(N));                       \
    __builtin_amdgcn_sched_barrier(0);                                   \
    s16x8 af = cvt8(a0_##S, a1_##S);                                     \
    acc[0] = mfma16(af, b0_##S, acc[0]);                                 \
    acc[1] = mfma16(af, b1_##S, acc[1]);                                 \
    acc[2] = mfma16(af, b2_##S, acc[2]);                                 \
    acc[3] = mfma16(af, b3_##S, acc[3]);                                 \
    __builtin_amdgcn_sched_barrier(0);                                   \
  }

  ISSUE(0, 0) ISSUE(1, 1) ISSUE(2, 2) ISSUE(3, 3)
  STEPC(0, 0, 18)  ISSUE(4, 0)
  STEPC(1, 1, 18)  ISSUE(5, 1)
  STEPC(2, 2, 18)  ISSUE(6, 2)
  STEPC(3, 3, 18)  ISSUE(7, 3)
  STEPC(4, 0, 18)  ISSUE(8, 0)
  STEPC(5, 1, 18)  ISSUE(9, 1)
  STEPC(6, 2, 18)  ISSUE(10, 2)
  STEPC(7, 3, 18)  ISSUE(11, 3)
  STEPC(8, 0, 18)  ISSUE(12, 0)
  STEPC(9, 1, 18)  ISSUE(13, 1)
  STEPC(10, 2, 18) ISSUE(14, 2)
  STEPC(11, 3, 18) ISSUE(15, 3)
  STEPC(12, 0, 18) ISSUE(16, 0)
  STEPC(13, 1, 18) ISSUE(17, 1)
  STEPC(14, 2, 18) ISSUE(18, 2)
  STEPC(15, 3, 18) ISSUE(19, 3)
  STEPC(16, 0, 18) ISSUE(20, 0)
  STEPC(17, 1, 18) ISSUE(21, 1)
  STEPC(18, 2, 18) ISSUE(22, 2)
  STEPC(19, 3, 18) ISSUE(23, 3)
  STEPC(20, 0, 18)
  STEPC(21, 1, 12)
  STEPC(22, 2, 6)
  STEPC(23, 3, 0)
#undef STEPC
#undef ISSUE
#undef GL

  // epilogue: bias, bf16 X write, 16-row column sumsq -> ps[unit]
#pragma unroll
  for (int ni = 0; ni < 4; ni++) {
    int col = wc * 64 + ni * 16 + llo;
    float bv = bias[col];
    float s = 0.f;
#pragma unroll
    for (int r = 0; r < 4; r++) {
      float xv = acc[ni][r] + bv;
      s += xv * xv;
      X[(size_t)(row0 + lhi * 4 + r) * D_ + col] = cvt_bf16(xv);
    }
    s += __shfl_xor(s, 16, 64);
    s += __shfl_xor(s, 32, 64);
    if (lhi == 0) ps[(size_t)unit * 128 + col] = s;
  }
}

// ---------------- K3: finalize norm + write bf16 V ----------------
// 1088 blocks of 32 rows; ps in 16-row units (2176 x 128).
__global__ __launch_bounds__(256) void k_normfin(
    const short* __restrict__ Xq, const short* __restrict__ Xp, const short* __restrict__ Xn,
    const float* __restrict__ ps,
    short* __restrict__ Vq, short* __restrict__ Vp, short* __restrict__ Vn) {
  __shared__ float invs[128];
  int bid = blockIdx.x;
  const short* X; short* V; int row0, pbase, pcnt;
  if (bid < 64)       { X = Xq; V = Vq; row0 = bid * 32;         pbase = bid * 2;                       pcnt = 2;  }
  else if (bid < 576) { X = Xp; V = Vp; row0 = (bid - 64) * 32;  pbase = 128 + ((bid - 64) / 8) * 16;   pcnt = 16; }
  else                { X = Xn; V = Vn; row0 = (bid - 576) * 32; pbase = 1152 + ((bid - 576) / 8) * 16; pcnt = 16; }
  int t = threadIdx.x;
  if (t < 128) {
    float s = 0.f;
    for (int j = 0; j < pcnt; j++) s += ps[(size_t)(pbase + j) * 128 + t];
    invs[t] = 1.0f / fmaxf(sqrtf(s), 1e-12f);
  }
  __syncthreads();
  int row = row0 + (t >> 3), c0 = (t & 7) << 4;
  const short* xr = X + (size_t)row * D_ + c0;
  s16x8 x0 = *(const s16x8*)(xr);
  s16x8 x1 = *(const s16x8*)(xr + 8);
  f32x4 i0 = *(const f32x4*)(&invs[c0]);
  f32x4 i1 = *(const f32x4*)(&invs[c0 + 4]);
  f32x4 i2 = *(const f32x4*)(&invs[c0 + 8]);
  f32x4 i3 = *(const f32x4*)(&invs[c0 + 12]);
  s16x8 o0, o1;
  for (int j = 0; j < 4; j++) {
    o0[j]     = cvt_bf16(frombf(x0[j])     * i0[j]);
    o0[j + 4] = cvt_bf16(frombf(x0[j + 4]) * i1[j]);
    o1[j]     = cvt_bf16(frombf(x1[j])     * i2[j]);
    o1[j + 4] = cvt_bf16(frombf(x1[j + 4]) * i3[j]);
  }
  short* vr = V + (size_t)row * D_ + c0;
  *(s16x8*)(vr) = o0;
  *(s16x8*)(vr + 8) = o1;
}

// ---------------- K4: MaxSim, swapped operands (P=A in LDS, Q=B in regs) ----------------
__global__ __launch_bounds__(512, 2) void k_maxsim(
    const short* __restrict__ QV, const short* __restrict__ PV, const short* __restrict__ NV,
    const float* __restrict__ MF, float* __restrict__ OUT) {
  __shared__ short Ps[LP_ * D_];  // 64 KB, XOR-swizzled (pitch 256 B)
  int t = threadIdx.x, lane = t & 63, w = t >> 6;
  int lhi = lane >> 4, llo = lane & 15;
  int c = blockIdx.x, side = blockIdx.y, quarter = blockIdx.z;
  const short* P = side ? NV : PV;
  const float* mfb = MF + (size_t)(side * B_ + c) * LP_;

  const short* qb = QV + (size_t)(quarter * 512 + w * 64) * D_;
  s16x8 bq[4][4];
  for (int ni = 0; ni < 4; ni++)
    for (int ks = 0; ks < 4; ks++)
      bq[ni][ks] = *(const s16x8*)(qb + (size_t)(ni * 16 + llo) * D_ + ks * 32 + lhi * 8);

  const short* src = P + (size_t)c * LP_ * D_;
  for (int i = 0; i < 8; i++) {
    int s = i * 512 + t;
    int p = s >> 4, kc = s & 15;
    s16x8 v = *(const s16x8*)(src + (size_t)p * D_ + kc * 8);
    int byteoff = (p * 256 + kc * 16) ^ ((p & 7) << 4);
    *(s16x8*)((char*)Ps + byteoff) = v;
  }
  __syncthreads();

  float ninf = -__builtin_inff();
  float rmax[4] = {ninf, ninf, ninf, ninf};
  for (int pi = 0; pi < 4; pi++) {
    f32x4 acc[4][4] = {};  // [mi][ni]
    for (int ks = 0; ks < 4; ks++) {
      s16x8 pa[4];
      for (int mi = 0; mi < 4; mi++) {
        int prow = pi * 64 + mi * 16 + llo;
        int off = (prow * 256 + ks * 64 + lhi * 16) ^ ((prow & 7) << 4);
        pa[mi] = *(const s16x8*)((char*)Ps + off);
      }
      __builtin_amdgcn_s_setprio(1);
      for (int mi = 0; mi < 4; mi++)
        for (int ni = 0; ni < 4; ni++)
          acc[mi][ni] = mfma16(pa[mi], bq[ni][ks], acc[mi][ni]);
      __builtin_amdgcn_s_setprio(0);
    }
    f32x4 mk[4];
    for (int mi = 0; mi < 4; mi++)
      mk[mi] = *(const f32x4*)(mfb + pi * 64 + mi * 16 + lhi * 4);
    for (int ni = 0; ni < 4; ni++)
      for (int mi = 0; mi < 4; mi++)
        for (int r = 0; r < 4; r++)
          rmax[ni] = fmaxf(rmax[ni], acc[mi][ni][r] + mk[mi][r]);
  }
  for (int ni = 0; ni < 4; ni++) {
    rmax[ni] = fmaxf(rmax[ni], __shfl_xor(rmax[ni], 16, 64));
    rmax[ni] = fmaxf(rmax[ni], __shfl_xor(rmax[ni], 32, 64));
  }
  float s0 = rmax[0] + rmax[1];
  float s1 = rmax[2] + rmax[3];
  for (int m = 1; m < 16; m <<= 1) {
    s0 += __shfl_xor(s0, m, 64);
    s1 += __shfl_xor(s1, m, 64);
  }
  if (lane == 0) {
    int b0 = quarter * 16 + w * 2;
    OUT[(size_t)b0 * 128 + side * 64 + c] = s0;
    OUT[(size_t)(b0 + 1) * 128 + side * 64 + c] = s1;
  }
}

extern "C" void kernel_launch(void* const* d_in, const int* in_sizes, int n_in,
                              void* d_out, int out_size, void* d_ws, size_t ws_size,
                              hipStream_t stream) {
  const float* qh = (const float*)d_in[0];
  const float* ph = (const float*)d_in[1];
  const float* nh = (const float*)d_in[2];
  const float* W  = (const float*)d_in[3];
  const float* bias = (const float*)d_in[4];
  const int* pm = (const int*)d_in[5];
  const int* nm = (const int*)d_in[6];
  float* out = (float*)d_out;
  char* ws = (char*)d_ws;

  short* Wt = (short*)(ws + 0x0);        // 128x768 bf16      192 KB
  float* mf = (float*)(ws + 0x30000);    // 2x64x256 f32      128 KB
  float* ps = (float*)(ws + 0x50000);    // 2176x128 f32      1.11 MB
  short* xq = (short*)(ws + 0x160000);   // 2048x128 bf16     512 KB
  short* xp = (short*)(ws + 0x1E0000);   // 16384x128 bf16    4 MB
  short* xn = (short*)(ws + 0x5E0000);   // 16384x128 bf16    4 MB
  short* qv = (short*)(ws + 0x9E0000);   // 2048x128 bf16     512 KB
  short* pv = (short*)(ws + 0xA60000);   // 16384x128 bf16    4 MB
  short* nv = (short*)(ws + 0xE60000);   // 16384x128 bf16    4 MB

  k_pre<<<160, 256, 0, stream>>>(W, pm, nm, Wt, mf);
  k_proj<<<1088, 256, 0, stream>>>(qh, ph, nh, Wt, bias, xq, xp, xn, ps);
  k_normfin<<<1088, 256, 0, stream>>>(xq, xp, xn, ps, qv, pv, nv);
  k_maxsim<<<dim3(64, 2, 4), 512, 0, stream>>>(qv, pv, nv, mf, out);
}

// Round 10
// 119.065 us; speedup vs baseline: 1.0007x; 1.0007x over previous
//
#include <hip/hip_runtime.h>

typedef __attribute__((ext_vector_type(4))) float f32x4;
typedef __attribute__((ext_vector_type(8))) short s16x8;
typedef __attribute__((ext_vector_type(4))) short s16x4;
typedef __attribute__((ext_vector_type(8))) __bf16 bf16x8;

#define B_ 64
#define LQ_ 32
#define LP_ 256
#define H_ 768
#define D_ 128

__device__ __forceinline__ short cvt_bf16(float f) {
  unsigned u = __builtin_bit_cast(unsigned, f);
  unsigned r = (u + 0x7fffu + ((u >> 16) & 1u)) >> 16;
  return (short)r;
}
__device__ __forceinline__ float frombf(short h) {
  unsigned v = ((unsigned)(unsigned short)h) << 16;
  return __builtin_bit_cast(float, v);
}
__device__ __forceinline__ f32x4 mfma16(s16x8 a, s16x8 b, f32x4 c) {
  return __builtin_amdgcn_mfma_f32_16x16x32_bf16(
      __builtin_bit_cast(bf16x8, a), __builtin_bit_cast(bf16x8, b), c, 0, 0, 0);
}
__device__ __forceinline__ s16x8 cvt8(f32x4 a, f32x4 b) {
  s16x8 r;
  r[0] = __builtin_bit_cast(short, (__bf16)a[0]);
  r[1] = __builtin_bit_cast(short, (__bf16)a[1]);
  r[2] = __builtin_bit_cast(short, (__bf16)a[2]);
  r[3] = __builtin_bit_cast(short, (__bf16)a[3]);
  r[4] = __builtin_bit_cast(short, (__bf16)b[0]);
  r[5] = __builtin_bit_cast(short, (__bf16)b[1]);
  r[6] = __builtin_bit_cast(short, (__bf16)b[2]);
  r[7] = __builtin_bit_cast(short, (__bf16)b[3]);
  return r;
}

// ---------------- K1: fused pre-work ----------------
__global__ __launch_bounds__(256) void k_pre(const float* __restrict__ W,
                                             const int* __restrict__ pm,
                                             const int* __restrict__ nm,
                                             short* __restrict__ Wt,
                                             float* __restrict__ mf) {
  __shared__ float tile[32][33];
  int bid = blockIdx.x;
  int t = threadIdx.x;
  if (bid < 96) {
    int k0 = (bid % 24) * 32, n0 = (bid / 24) * 32;
    int r = t >> 3, c4 = (t & 7) << 2;
    f32x4 v = *(const f32x4*)(W + (size_t)(k0 + r) * D_ + n0 + c4);
    tile[r][c4 + 0] = v[0]; tile[r][c4 + 1] = v[1];
    tile[r][c4 + 2] = v[2]; tile[r][c4 + 3] = v[3];
    __syncthreads();
    s16x4 o;
    o[0] = cvt_bf16(tile[c4 + 0][r]);
    o[1] = cvt_bf16(tile[c4 + 1][r]);
    o[2] = cvt_bf16(tile[c4 + 2][r]);
    o[3] = cvt_bf16(tile[c4 + 3][r]);
    *(s16x4*)(Wt + (size_t)(n0 + r) * H_ + k0 + c4) = o;
  } else {
    int i = (bid - 96) * 256 + t;
    float ninf = -__builtin_inff();
    mf[i]         = pm[i] ? 0.f : ninf;
    mf[16384 + i] = nm[i] ? 0.f : ninf;
  }
}

// ---------------- K2: projection GEMM — inline-asm loads, counted vmcnt ----------------
// Same as round 9 EXCEPT __launch_bounds__(256, 2): VGPR budget 256 so the 4
// named slots (~160 VGPR) + acc + addresses fit WITHOUT spilling (r9 spilled at
// the 168-reg budget of min-waves=3 -> scratch round-trips, 99us).
__global__ __launch_bounds__(256, 2) void k_proj(
    const float* __restrict__ Hq, const float* __restrict__ Hp, const float* __restrict__ Hn,
    const short* __restrict__ Wt, const float* __restrict__ bias,
    short* __restrict__ Xq, short* __restrict__ Xp, short* __restrict__ Xn,
    float* __restrict__ ps) {
  int bid = blockIdx.x;
  const float* Hs; short* X; int brow0, ub;
  if (bid < 64)       { Hs = Hq; X = Xq; brow0 = bid * 32;         ub = bid * 2; }
  else if (bid < 576) { Hs = Hp; X = Xp; brow0 = (bid - 64) * 32;  ub = 128 + (bid - 64) * 2; }
  else                { Hs = Hn; X = Xn; brow0 = (bid - 576) * 32; ub = 1152 + (bid - 576) * 2; }
  int t = threadIdx.x, lane = t & 63, w = t >> 6;
  int wm = w & 1, wc = w >> 1;
  int lhi = lane >> 4, llo = lane & 15;
  int row0 = brow0 + wm * 16;
  int unit = ub + wm;

  const float* ap  = Hs + (size_t)(row0 + llo) * H_ + lhi * 8;
  const short* bp0 = Wt + (size_t)(wc * 64 + llo) * H_ + lhi * 8;
  const short* bp1 = bp0 + (size_t)16 * H_;
  const short* bp2 = bp0 + (size_t)32 * H_;
  const short* bp3 = bp0 + (size_t)48 * H_;

  // 4 slots, all named (volatile asm outputs -> ordered, not sinkable)
  f32x4 a0_0, a1_0, a0_1, a1_1, a0_2, a1_2, a0_3, a1_3;
  s16x8 b0_0, b1_0, b2_0, b3_0, b0_1, b1_1, b2_1, b3_1;
  s16x8 b0_2, b1_2, b2_2, b3_2, b0_3, b1_3, b2_3, b3_3;

#define GL(dst, base, OFF)                                               \
  asm volatile("global_load_dwordx4 %0, %1, off offset:%2"               \
               : "=&v"(dst) : "v"(base), "n"(OFF));

#define ISSUE(C, S)                                                      \
  GL(a0_##S, ap,  (C) * 128)                                             \
  GL(a1_##S, ap,  (C) * 128 + 16)                                        \
  GL(b0_##S, bp0, (C) * 64)                                              \
  GL(b1_##S, bp1, (C) * 64)                                              \
  GL(b2_##S, bp2, (C) * 64)                                              \
  GL(b3_##S, bp3, (C) * 64)

  f32x4 acc[4] = {};

#define STEPC(C, S, N)                                                   \
  {                                                                      \
    asm volatile("s_waitcnt vmcnt(%0)" :: "n"(N));                       \
    __builtin_amdgcn_sched_barrier(0);                                   \
    s16x8 af = cvt8(a0_##S, a1_##S);                                     \
    acc[0] = mfma16(af, b0_##S, acc[0]);                                 \
    acc[1] = mfma16(af, b1_##S, acc[1]);                                 \
    acc[2] = mfma16(af, b2_##S, acc[2]);                                 \
    acc[3] = mfma16(af, b3_##S, acc[3]);                                 \
    __builtin_amdgcn_sched_barrier(0);                                   \
  }

  ISSUE(0, 0) ISSUE(1, 1) ISSUE(2, 2) ISSUE(3, 3)
  STEPC(0, 0, 18)  ISSUE(4, 0)
  STEPC(1, 1, 18)  ISSUE(5, 1)
  STEPC(2, 2, 18)  ISSUE(6, 2)
  STEPC(3, 3, 18)  ISSUE(7, 3)
  STEPC(4, 0, 18)  ISSUE(8, 0)
  STEPC(5, 1, 18)  ISSUE(9, 1)
  STEPC(6, 2, 18)  ISSUE(10, 2)
  STEPC(7, 3, 18)  ISSUE(11, 3)
  STEPC(8, 0, 18)  ISSUE(12, 0)
  STEPC(9, 1, 18)  ISSUE(13, 1)
  STEPC(10, 2, 18) ISSUE(14, 2)
  STEPC(11, 3, 18) ISSUE(15, 3)
  STEPC(12, 0, 18) ISSUE(16, 0)
  STEPC(13, 1, 18) ISSUE(17, 1)
  STEPC(14, 2, 18) ISSUE(18, 2)
  STEPC(15, 3, 18) ISSUE(19, 3)
  STEPC(16, 0, 18) ISSUE(20, 0)
  STEPC(17, 1, 18) ISSUE(21, 1)
  STEPC(18, 2, 18) ISSUE(22, 2)
  STEPC(19, 3, 18) ISSUE(23, 3)
  STEPC(20, 0, 18)
  STEPC(21, 1, 12)
  STEPC(22, 2, 6)
  STEPC(23, 3, 0)
#undef STEPC
#undef ISSUE
#undef GL

  // epilogue: bias, bf16 X write, 16-row column sumsq -> ps[unit]
#pragma unroll
  for (int ni = 0; ni < 4; ni++) {
    int col = wc * 64 + ni * 16 + llo;
    float bv = bias[col];
    float s = 0.f;
#pragma unroll
    for (int r = 0; r < 4; r++) {
      float xv = acc[ni][r] + bv;
      s += xv * xv;
      X[(size_t)(row0 + lhi * 4 + r) * D_ + col] = cvt_bf16(xv);
    }
    s += __shfl_xor(s, 16, 64);
    s += __shfl_xor(s, 32, 64);
    if (lhi == 0) ps[(size_t)unit * 128 + col] = s;
  }
}

// ---------------- K3: finalize norm + write bf16 V ----------------
// 1088 blocks of 32 rows; ps in 16-row units (2176 x 128).
__global__ __launch_bounds__(256) void k_normfin(
    const short* __restrict__ Xq, const short* __restrict__ Xp, const short* __restrict__ Xn,
    const float* __restrict__ ps,
    short* __restrict__ Vq, short* __restrict__ Vp, short* __restrict__ Vn) {
  __shared__ float invs[128];
  int bid = blockIdx.x;
  const short* X; short* V; int row0, pbase, pcnt;
  if (bid < 64)       { X = Xq; V = Vq; row0 = bid * 32;         pbase = bid * 2;                       pcnt = 2;  }
  else if (bid < 576) { X = Xp; V = Vp; row0 = (bid - 64) * 32;  pbase = 128 + ((bid - 64) / 8) * 16;   pcnt = 16; }
  else                { X = Xn; V = Vn; row0 = (bid - 576) * 32; pbase = 1152 + ((bid - 576) / 8) * 16; pcnt = 16; }
  int t = threadIdx.x;
  if (t < 128) {
    float s = 0.f;
    for (int j = 0; j < pcnt; j++) s += ps[(size_t)(pbase + j) * 128 + t];
    invs[t] = 1.0f / fmaxf(sqrtf(s), 1e-12f);
  }
  __syncthreads();
  int row = row0 + (t >> 3), c0 = (t & 7) << 4;
  const short* xr = X + (size_t)row * D_ + c0;
  s16x8 x0 = *(const s16x8*)(xr);
  s16x8 x1 = *(const s16x8*)(xr + 8);
  f32x4 i0 = *(const f32x4*)(&invs[c0]);
  f32x4 i1 = *(const f32x4*)(&invs[c0 + 4]);
  f32x4 i2 = *(const f32x4*)(&invs[c0 + 8]);
  f32x4 i3 = *(const f32x4*)(&invs[c0 + 12]);
  s16x8 o0, o1;
  for (int j = 0; j < 4; j++) {
    o0[j]     = cvt_bf16(frombf(x0[j])     * i0[j]);
    o0[j + 4] = cvt_bf16(frombf(x0[j + 4]) * i1[j]);
    o1[j]     = cvt_bf16(frombf(x1[j])     * i2[j]);
    o1[j + 4] = cvt_bf16(frombf(x1[j + 4]) * i3[j]);
  }
  short* vr = V + (size_t)row * D_ + c0;
  *(s16x8*)(vr) = o0;
  *(s16x8*)(vr + 8) = o1;
}

// ---------------- K4: MaxSim, swapped operands (P=A in LDS, Q=B in regs) ----------------
__global__ __launch_bounds__(512, 2) void k_maxsim(
    const short* __restrict__ QV, const short* __restrict__ PV, const short* __restrict__ NV,
    const float* __restrict__ MF, float* __restrict__ OUT) {
  __shared__ short Ps[LP_ * D_];  // 64 KB, XOR-swizzled (pitch 256 B)
  int t = threadIdx.x, lane = t & 63, w = t >> 6;
  int lhi = lane >> 4, llo = lane & 15;
  int c = blockIdx.x, side = blockIdx.y, quarter = blockIdx.z;
  const short* P = side ? NV : PV;
  const float* mfb = MF + (size_t)(side * B_ + c) * LP_;

  const short* qb = QV + (size_t)(quarter * 512 + w * 64) * D_;
  s16x8 bq[4][4];
  for (int ni = 0; ni < 4; ni++)
    for (int ks = 0; ks < 4; ks++)
      bq[ni][ks] = *(const s16x8*)(qb + (size_t)(ni * 16 + llo) * D_ + ks * 32 + lhi * 8);

  const short* src = P + (size_t)c * LP_ * D_;
  for (int i = 0; i < 8; i++) {
    int s = i * 512 + t;
    int p = s >> 4, kc = s & 15;
    s16x8 v = *(const s16x8*)(src + (size_t)p * D_ + kc * 8);
    int byteoff = (p * 256 + kc * 16) ^ ((p & 7) << 4);
    *(s16x8*)((char*)Ps + byteoff) = v;
  }
  __syncthreads();

  float ninf = -__builtin_inff();
  float rmax[4] = {ninf, ninf, ninf, ninf};
  for (int pi = 0; pi < 4; pi++) {
    f32x4 acc[4][4] = {};  // [mi][ni]
    for (int ks = 0; ks < 4; ks++) {
      s16x8 pa[4];
      for (int mi = 0; mi < 4; mi++) {
        int prow = pi * 64 + mi * 16 + llo;
        int off = (prow * 256 + ks * 64 + lhi * 16) ^ ((prow & 7) << 4);
        pa[mi] = *(const s16x8*)((char*)Ps + off);
      }
      __builtin_amdgcn_s_setprio(1);
      for (int mi = 0; mi < 4; mi++)
        for (int ni = 0; ni < 4; ni++)
          acc[mi][ni] = mfma16(pa[mi], bq[ni][ks], acc[mi][ni]);
      __builtin_amdgcn_s_setprio(0);
    }
    f32x4 mk[4];
    for (int mi = 0; mi < 4; mi++)
      mk[mi] = *(const f32x4*)(mfb + pi * 64 + mi * 16 + lhi * 4);
    for (int ni = 0; ni < 4; ni++)
      for (int mi = 0; mi < 4; mi++)
        for (int r = 0; r < 4; r++)
          rmax[ni] = fmaxf(rmax[ni], acc[mi][ni][r] + mk[mi][r]);
  }
  for (int ni = 0; ni < 4; ni++) {
    rmax[ni] = fmaxf(rmax[ni], __shfl_xor(rmax[ni], 16, 64));
    rmax[ni] = fmaxf(rmax[ni], __shfl_xor(rmax[ni], 32, 64));
  }
  float s0 = rmax[0] + rmax[1];
  float s1 = rmax[2] + rmax[3];
  for (int m = 1; m < 16; m <<= 1) {
    s0 += __shfl_xor(s0, m, 64);
    s1 += __shfl_xor(s1, m, 64);
  }
  if (lane == 0) {
    int b0 = quarter * 16 + w * 2;
    OUT[(size_t)b0 * 128 + side * 64 + c] = s0;
    OUT[(size_t)(b0 + 1) * 128 + side * 64 + c] = s1;
  }
}

extern "C" void kernel_launch(void* const* d_in, const int* in_sizes, int n_in,
                              void* d_out, int out_size, void* d_ws, size_t ws_size,
                              hipStream_t stream) {
  const float* qh = (const float*)d_in[0];
  const float* ph = (const float*)d_in[1];
  const float* nh = (const float*)d_in[2];
  const float* W  = (const float*)d_in[3];
  const float* bias = (const float*)d_in[4];
  const int* pm = (const int*)d_in[5];
  const int* nm = (const int*)d_in[6];
  float* out = (float*)d_out;
  char* ws = (char*)d_ws;

  short* Wt = (short*)(ws + 0x0);        // 128x768 bf16      192 KB
  float* mf = (float*)(ws + 0x30000);    // 2x64x256 f32      128 KB
  float* ps = (float*)(ws + 0x50000);    // 2176x128 f32      1.11 MB
  short* xq = (short*)(ws + 0x160000);   // 2048x128 bf16     512 KB
  short* xp = (short*)(ws + 0x1E0000);   // 16384x128 bf16    4 MB
  short* xn = (short*)(ws + 0x5E0000);   // 16384x128 bf16    4 MB
  short* qv = (short*)(ws + 0x9E0000);   // 2048x128 bf16     512 KB
  short* pv = (short*)(ws + 0xA60000);   // 16384x128 bf16    4 MB
  short* nv = (short*)(ws + 0xE60000);   // 16384x128 bf16    4 MB

  k_pre<<<160, 256, 0, stream>>>(W, pm, nm, Wt, mf);
  k_proj<<<1088, 256, 0, stream>>>(qh, ph, nh, Wt, bias, xq, xp, xn, ps);
  k_normfin<<<1088, 256, 0, stream>>>(xq, xp, xn, ps, qv, pv, nv);
  k_maxsim<<<dim3(64, 2, 4), 512, 0, stream>>>(qv, pv, nv, mf, out);
}

// Round 11
// 116.637 us; speedup vs baseline: 1.0215x; 1.0208x over previous
//
#include <hip/hip_runtime.h>

typedef __attribute__((ext_vector_type(4))) float f32x4;
typedef __attribute__((ext_vector_type(8))) short s16x8;
typedef __attribute__((ext_vector_type(4))) short s16x4;
typedef __attribute__((ext_vector_type(8))) __bf16 bf16x8;

#define B_ 64
#define LQ_ 32
#define LP_ 256
#define H_ 768
#define D_ 128

__device__ __forceinline__ short cvt_bf16(float f) {
  unsigned u = __builtin_bit_cast(unsigned, f);
  unsigned r = (u + 0x7fffu + ((u >> 16) & 1u)) >> 16;
  return (short)r;
}
__device__ __forceinline__ float frombf(short h) {
  unsigned v = ((unsigned)(unsigned short)h) << 16;
  return __builtin_bit_cast(float, v);
}
__device__ __forceinline__ f32x4 mfma16(s16x8 a, s16x8 b, f32x4 c) {
  return __builtin_amdgcn_mfma_f32_16x16x32_bf16(
      __builtin_bit_cast(bf16x8, a), __builtin_bit_cast(bf16x8, b), c, 0, 0, 0);
}
__device__ __forceinline__ s16x8 cvt8(f32x4 a, f32x4 b) {
  s16x8 r;
  r[0] = __builtin_bit_cast(short, (__bf16)a[0]);
  r[1] = __builtin_bit_cast(short, (__bf16)a[1]);
  r[2] = __builtin_bit_cast(short, (__bf16)a[2]);
  r[3] = __builtin_bit_cast(short, (__bf16)a[3]);
  r[4] = __builtin_bit_cast(short, (__bf16)b[0]);
  r[5] = __builtin_bit_cast(short, (__bf16)b[1]);
  r[6] = __builtin_bit_cast(short, (__bf16)b[2]);
  r[7] = __builtin_bit_cast(short, (__bf16)b[3]);
  return r;
}

// ---------------- K1: fused pre-work ----------------
__global__ __launch_bounds__(256) void k_pre(const float* __restrict__ W,
                                             const int* __restrict__ pm,
                                             const int* __restrict__ nm,
                                             short* __restrict__ Wt,
                                             float* __restrict__ mf) {
  __shared__ float tile[32][33];
  int bid = blockIdx.x;
  int t = threadIdx.x;
  if (bid < 96) {
    int k0 = (bid % 24) * 32, n0 = (bid / 24) * 32;
    int r = t >> 3, c4 = (t & 7) << 2;
    f32x4 v = *(const f32x4*)(W + (size_t)(k0 + r) * D_ + n0 + c4);
    tile[r][c4 + 0] = v[0]; tile[r][c4 + 1] = v[1];
    tile[r][c4 + 2] = v[2]; tile[r][c4 + 3] = v[3];
    __syncthreads();
    s16x4 o;
    o[0] = cvt_bf16(tile[c4 + 0][r]);
    o[1] = cvt_bf16(tile[c4 + 1][r]);
    o[2] = cvt_bf16(tile[c4 + 2][r]);
    o[3] = cvt_bf16(tile[c4 + 3][r]);
    *(s16x4*)(Wt + (size_t)(n0 + r) * H_ + k0 + c4) = o;
  } else {
    int i = (bid - 96) * 256 + t;
    float ninf = -__builtin_inff();
    mf[i]         = pm[i] ? 0.f : ninf;
    mf[16384 + i] = nm[i] ? 0.f : ninf;
  }
}

// ---------------- K2: projection GEMM — pure-TLP streaming ----------------
// 1088 blocks x 256 thr = 4352 INDEPENDENT waves (no LDS, no barriers).
// Wave = 32 rows x 32 cols (one col-quarter q). 24 BK=32 chunks, plain
// unrolled loop: 6 loads + 2 cvt + 4 MFMA per chunk, immediate offsets.
// Latency hiding comes from 16 waves/CU TLP (96 KB in flight/CU when all
// waves stall), NOT from per-wave pipelining (rounds 4-10 proved hipcc
// collapses/spills every per-wave scheme).
__global__ __launch_bounds__(256, 4) void k_proj(
    const float* __restrict__ Hq, const float* __restrict__ Hp, const float* __restrict__ Hn,
    const short* __restrict__ Wt, const float* __restrict__ bias,
    short* __restrict__ Xq, short* __restrict__ Xp, short* __restrict__ Xn,
    float* __restrict__ ps) {
  int bid = blockIdx.x;
  const float* Hs; short* X; int row0;
  if (bid < 64)       { Hs = Hq; X = Xq; row0 = bid * 32; }
  else if (bid < 576) { Hs = Hp; X = Xp; row0 = (bid - 64) * 32; }
  else                { Hs = Hn; X = Xn; row0 = (bid - 576) * 32; }
  int t = threadIdx.x, lane = t & 63, q = t >> 6;  // q = col quarter
  int lhi = lane >> 4, llo = lane & 15;

  const float* ap0 = Hs + (size_t)(row0 + llo) * H_ + lhi * 8;  // rows 0..15
  const float* ap1 = ap0 + (size_t)16 * H_;                     // rows 16..31
  const short* bp0 = Wt + (size_t)(q * 32 + llo) * H_ + lhi * 8;
  const short* bp1 = bp0 + (size_t)16 * H_;

  f32x4 acc[2][2] = {};
#pragma unroll
  for (int c = 0; c < 24; ++c) {
    f32x4 a00 = *(const f32x4*)(ap0 + c * 32);
    f32x4 a01 = *(const f32x4*)(ap0 + c * 32 + 4);
    f32x4 a10 = *(const f32x4*)(ap1 + c * 32);
    f32x4 a11 = *(const f32x4*)(ap1 + c * 32 + 4);
    s16x8 b0 = *(const s16x8*)(bp0 + c * 32);
    s16x8 b1 = *(const s16x8*)(bp1 + c * 32);
    s16x8 af0 = cvt8(a00, a01);
    s16x8 af1 = cvt8(a10, a11);
    acc[0][0] = mfma16(af0, b0, acc[0][0]);
    acc[0][1] = mfma16(af0, b1, acc[0][1]);
    acc[1][0] = mfma16(af1, b0, acc[1][0]);
    acc[1][1] = mfma16(af1, b1, acc[1][1]);
  }

  // epilogue: bias, bf16 X write, column sumsq partial (cols q*32..+31)
#pragma unroll
  for (int ni = 0; ni < 2; ni++) {
    int col = q * 32 + ni * 16 + llo;
    float bv = bias[col];
    float s = 0.f;
#pragma unroll
    for (int mi = 0; mi < 2; mi++)
      for (int r = 0; r < 4; r++) {
        float xv = acc[mi][ni][r] + bv;
        s += xv * xv;
        X[(size_t)(row0 + mi * 16 + lhi * 4 + r) * D_ + col] = cvt_bf16(xv);
      }
    s += __shfl_xor(s, 16, 64);
    s += __shfl_xor(s, 32, 64);
    if (lhi == 0) ps[(size_t)bid * 128 + col] = s;
  }
}

// ---------------- K3: finalize norm + write bf16 V ----------------
// 1088 blocks of 32 rows; ps in 32-row units (1088 x 128), unit == bid.
__global__ __launch_bounds__(256) void k_normfin(
    const short* __restrict__ Xq, const short* __restrict__ Xp, const short* __restrict__ Xn,
    const float* __restrict__ ps,
    short* __restrict__ Vq, short* __restrict__ Vp, short* __restrict__ Vn) {
  __shared__ float invs[128];
  int bid = blockIdx.x;
  const short* X; short* V; int row0, pbase, pcnt;
  if (bid < 64)       { X = Xq; V = Vq; row0 = bid * 32;         pbase = bid;                        pcnt = 1; }
  else if (bid < 576) { X = Xp; V = Vp; row0 = (bid - 64) * 32;  pbase = 64 + ((bid - 64) & ~7);     pcnt = 8; }
  else                { X = Xn; V = Vn; row0 = (bid - 576) * 32; pbase = 576 + ((bid - 576) & ~7);   pcnt = 8; }
  int t = threadIdx.x;
  if (t < 128) {
    float s = 0.f;
    for (int j = 0; j < pcnt; j++) s += ps[(size_t)(pbase + j) * 128 + t];
    invs[t] = 1.0f / fmaxf(sqrtf(s), 1e-12f);
  }
  __syncthreads();
  int row = row0 + (t >> 3), c0 = (t & 7) << 4;
  const short* xr = X + (size_t)row * D_ + c0;
  s16x8 x0 = *(const s16x8*)(xr);
  s16x8 x1 = *(const s16x8*)(xr + 8);
  f32x4 i0 = *(const f32x4*)(&invs[c0]);
  f32x4 i1 = *(const f32x4*)(&invs[c0 + 4]);
  f32x4 i2 = *(const f32x4*)(&invs[c0 + 8]);
  f32x4 i3 = *(const f32x4*)(&invs[c0 + 12]);
  s16x8 o0, o1;
  for (int j = 0; j < 4; j++) {
    o0[j]     = cvt_bf16(frombf(x0[j])     * i0[j]);
    o0[j + 4] = cvt_bf16(frombf(x0[j + 4]) * i1[j]);
    o1[j]     = cvt_bf16(frombf(x1[j])     * i2[j]);
    o1[j + 4] = cvt_bf16(frombf(x1[j + 4]) * i3[j]);
  }
  short* vr = V + (size_t)row * D_ + c0;
  *(s16x8*)(vr) = o0;
  *(s16x8*)(vr + 8) = o1;
}

// ---------------- K4: MaxSim, swapped operands (P=A in LDS, Q=B in regs) ----------------
__global__ __launch_bounds__(512, 2) void k_maxsim(
    const short* __restrict__ QV, const short* __restrict__ PV, const short* __restrict__ NV,
    const float* __restrict__ MF, float* __restrict__ OUT) {
  __shared__ short Ps[LP_ * D_];  // 64 KB, XOR-swizzled (pitch 256 B)
  int t = threadIdx.x, lane = t & 63, w = t >> 6;
  int lhi = lane >> 4, llo = lane & 15;
  int c = blockIdx.x, side = blockIdx.y, quarter = blockIdx.z;
  const short* P = side ? NV : PV;
  const float* mfb = MF + (size_t)(side * B_ + c) * LP_;

  const short* qb = QV + (size_t)(quarter * 512 + w * 64) * D_;
  s16x8 bq[4][4];
  for (int ni = 0; ni < 4; ni++)
    for (int ks = 0; ks < 4; ks++)
      bq[ni][ks] = *(const s16x8*)(qb + (size_t)(ni * 16 + llo) * D_ + ks * 32 + lhi * 8);

  const short* src = P + (size_t)c * LP_ * D_;
  for (int i = 0; i < 8; i++) {
    int s = i * 512 + t;
    int p = s >> 4, kc = s & 15;
    s16x8 v = *(const s16x8*)(src + (size_t)p * D_ + kc * 8);
    int byteoff = (p * 256 + kc * 16) ^ ((p & 7) << 4);
    *(s16x8*)((char*)Ps + byteoff) = v;
  }
  __syncthreads();

  float ninf = -__builtin_inff();
  float rmax[4] = {ninf, ninf, ninf, ninf};
  for (int pi = 0; pi < 4; pi++) {
    f32x4 acc[4][4] = {};  // [mi][ni]
    for (int ks = 0; ks < 4; ks++) {
      s16x8 pa[4];
      for (int mi = 0; mi < 4; mi++) {
        int prow = pi * 64 + mi * 16 + llo;
        int off = (prow * 256 + ks * 64 + lhi * 16) ^ ((prow & 7) << 4);
        pa[mi] = *(const s16x8*)((char*)Ps + off);
      }
      __builtin_amdgcn_s_setprio(1);
      for (int mi = 0; mi < 4; mi++)
        for (int ni = 0; ni < 4; ni++)
          acc[mi][ni] = mfma16(pa[mi], bq[ni][ks], acc[mi][ni]);
      __builtin_amdgcn_s_setprio(0);
    }
    f32x4 mk[4];
    for (int mi = 0; mi < 4; mi++)
      mk[mi] = *(const f32x4*)(mfb + pi * 64 + mi * 16 + lhi * 4);
    for (int ni = 0; ni < 4; ni++)
      for (int mi = 0; mi < 4; mi++)
        for (int r = 0; r < 4; r++)
          rmax[ni] = fmaxf(rmax[ni], acc[mi][ni][r] + mk[mi][r]);
  }
  for (int ni = 0; ni < 4; ni++) {
    rmax[ni] = fmaxf(rmax[ni], __shfl_xor(rmax[ni], 16, 64));
    rmax[ni] = fmaxf(rmax[ni], __shfl_xor(rmax[ni], 32, 64));
  }
  float s0 = rmax[0] + rmax[1];
  float s1 = rmax[2] + rmax[3];
  for (int m = 1; m < 16; m <<= 1) {
    s0 += __shfl_xor(s0, m, 64);
    s1 += __shfl_xor(s1, m, 64);
  }
  if (lane == 0) {
    int b0 = quarter * 16 + w * 2;
    OUT[(size_t)b0 * 128 + side * 64 + c] = s0;
    OUT[(size_t)(b0 + 1) * 128 + side * 64 + c] = s1;
  }
}

extern "C" void kernel_launch(void* const* d_in, const int* in_sizes, int n_in,
                              void* d_out, int out_size, void* d_ws, size_t ws_size,
                              hipStream_t stream) {
  const float* qh = (const float*)d_in[0];
  const float* ph = (const float*)d_in[1];
  const float* nh = (const float*)d_in[2];
  const float* W  = (const float*)d_in[3];
  const float* bias = (const float*)d_in[4];
  const int* pm = (const int*)d_in[5];
  const int* nm = (const int*)d_in[6];
  float* out = (float*)d_out;
  char* ws = (char*)d_ws;

  short* Wt = (short*)(ws + 0x0);        // 128x768 bf16      192 KB
  float* mf = (float*)(ws + 0x30000);    // 2x64x256 f32      128 KB
  float* ps = (float*)(ws + 0x50000);    // 1088x128 f32      557 KB
  short* xq = (short*)(ws + 0x160000);   // 2048x128 bf16     512 KB
  short* xp = (short*)(ws + 0x1E0000);   // 16384x128 bf16    4 MB
  short* xn = (short*)(ws + 0x5E0000);   // 16384x128 bf16    4 MB
  short* qv = (short*)(ws + 0x9E0000);   // 2048x128 bf16     512 KB
  short* pv = (short*)(ws + 0xA60000);   // 16384x128 bf16    4 MB
  short* nv = (short*)(ws + 0xE60000);   // 16384x128 bf16    4 MB

  k_pre<<<160, 256, 0, stream>>>(W, pm, nm, Wt, mf);
  k_proj<<<1088, 256, 0, stream>>>(qh, ph, nh, Wt, bias, xq, xp, xn, ps);
  k_normfin<<<1088, 256, 0, stream>>>(xq, xp, xn, ps, qv, pv, nv);
  k_maxsim<<<dim3(64, 2, 4), 512, 0, stream>>>(qv, pv, nv, mf, out);
}